// Round 1
// baseline (679.771 us; speedup 1.0000x reference)
//
#include <hip/hip_runtime.h>
#include <hip/hip_bf16.h>

// Problem constants (xlm-roberta-base temprel head)
#define BB 256      // batch
#define SS 512      // seq len
#define DD 768      // hidden
#define H1 256      // linear1 out
#define H2 64       // linear2 out
#define LL 4        // labels
#define K1 (4*DD)   // 3072 = concat feature dim
#define KC 16       // K-chunks for layer1 split-K
#define KCH (K1/KC) // 192
#define RT 16       // rows per block in layer1

// ---------------------------------------------------------------------------
// Kernel 1: event features. grid (B, 2), block 192 (one float4 lane per thread)
// h[b, which*1536 + 0:768]   = x[b, 0, :]            (CLS)
// h[b, which*1536 + 768:1536] = mean(x[b, s:e, :])   (segment mean)
// ---------------------------------------------------------------------------
__global__ void feat_kernel(const float4* __restrict__ x1,
                            const float4* __restrict__ x2,
                            const int* __restrict__ s1, const int* __restrict__ e1,
                            const int* __restrict__ s2, const int* __restrict__ e2,
                            float4* __restrict__ h) {
    const int b = blockIdx.x;
    const int which = blockIdx.y;
    const int t = threadIdx.x;  // 0..191  (768/4)
    const float4* x = which ? x2 : x1;
    int s = which ? s2[b] : s1[b];
    int e = which ? e2[b] : e1[b];
    e = max(e, s + 1);              // reference: end = max(end, start+1)
    const int sc = max(s, 0);
    const int ec = min(e, SS);
    const int n  = max(ec - sc, 1); // reference: cnt = max(mask.sum, 1)

    const float4* xrow = x + (size_t)b * SS * (DD/4);
    float4 cls = xrow[t];
    float4 acc = make_float4(0.f, 0.f, 0.f, 0.f);
    for (int p = sc; p < ec; ++p) {
        float4 v = xrow[(size_t)p * (DD/4) + t];
        acc.x += v.x; acc.y += v.y; acc.z += v.z; acc.w += v.w;
    }
    const float inv = 1.0f / (float)n;
    acc.x *= inv; acc.y *= inv; acc.z *= inv; acc.w *= inv;

    float4* hrow = h + (size_t)b * (K1/4) + which * (2*DD/4);
    hrow[t] = cls;
    hrow[(DD/4) + t] = acc;
}

// ---------------------------------------------------------------------------
// Kernel 2: layer-1 split-K partial GEMM.
// grid (B/RT=16, KC=16) = 256 blocks, block = 256 threads (one col each).
// Each block: rows r0..r0+15, all 256 cols, K-chunk of 192.
// h[] accesses are block-uniform -> scalar loads; W1 reads coalesced per k.
// partial[kc][row][col] fp32.
// ---------------------------------------------------------------------------
__global__ void layer1_kernel(const float* __restrict__ h,
                              const float* __restrict__ W1,
                              float* __restrict__ partial) {
    const int rt = blockIdx.x;    // row tile
    const int kc = blockIdx.y;    // k chunk
    const int j  = threadIdx.x;   // output column 0..255
    const int r0 = rt * RT;
    const int k0 = kc * KCH;

    float acc[RT];
#pragma unroll
    for (int r = 0; r < RT; ++r) acc[r] = 0.f;

    const float* w = W1 + (size_t)k0 * H1 + j;
    const float* hp = h + (size_t)r0 * K1 + k0;
#pragma unroll 8
    for (int k = 0; k < KCH; ++k) {
        const float wv = w[(size_t)k * H1];
#pragma unroll
        for (int r = 0; r < RT; ++r) {
            acc[r] = fmaf(hp[(size_t)r * K1 + k], wv, acc[r]);
        }
    }

    float* p = partial + ((size_t)kc * BB + r0) * H1 + j;
#pragma unroll
    for (int r = 0; r < RT; ++r) p[(size_t)r * H1] = acc[r];
}

// ---------------------------------------------------------------------------
// Kernel 3: fused head. grid (B), block 256.
// reduce split-K partials + b1 + relu -> a1[256] (LDS)
// a1 @ W2 + b2, relu -> a2[64] (LDS)
// a2 @ W3 + b3 -> logits[4] -> softmax -> out[b, 0:4]
// ---------------------------------------------------------------------------
__global__ void head_kernel(const float* __restrict__ partial,
                            const float* __restrict__ b1,
                            const float* __restrict__ W2,
                            const float* __restrict__ b2,
                            const float* __restrict__ W3,
                            const float* __restrict__ b3,
                            float* __restrict__ out) {
    const int b = blockIdx.x;
    const int t = threadIdx.x;
    __shared__ float a1[H1];
    __shared__ float a2[H2];
    __shared__ float lg[LL];

    float v = b1[t];
#pragma unroll
    for (int kc = 0; kc < KC; ++kc)
        v += partial[((size_t)kc * BB + b) * H1 + t];
    a1[t] = fmaxf(v, 0.f);
    __syncthreads();

    if (t < H2) {
        float acc = b2[t];
#pragma unroll 4
        for (int k = 0; k < H1; ++k)
            acc = fmaf(a1[k], W2[k * H2 + t], acc);
        a2[t] = fmaxf(acc, 0.f);
    }
    __syncthreads();

    if (t < LL) {
        float acc = b3[t];
#pragma unroll
        for (int k = 0; k < H2; ++k)
            acc = fmaf(a2[k], W3[k * LL + t], acc);
        lg[t] = acc;
    }
    __syncthreads();

    if (t < LL) {
        const float m = fmaxf(fmaxf(lg[0], lg[1]), fmaxf(lg[2], lg[3]));
        const float e0 = expf(lg[0] - m);
        const float e1v = expf(lg[1] - m);
        const float e2v = expf(lg[2] - m);
        const float e3 = expf(lg[3] - m);
        const float sum = e0 + e1v + e2v + e3;
        out[b * LL + t] = expf(lg[t] - m) / sum;
    }
}

extern "C" void kernel_launch(void* const* d_in, const int* in_sizes, int n_in,
                              void* d_out, int out_size, void* d_ws, size_t ws_size,
                              hipStream_t stream) {
    const float* x1 = (const float*)d_in[0];
    const float* x2 = (const float*)d_in[1];
    const int*   s1 = (const int*)d_in[2];
    const int*   e1 = (const int*)d_in[3];
    const int*   s2 = (const int*)d_in[4];
    const int*   e2 = (const int*)d_in[5];
    const float* W1 = (const float*)d_in[6];
    const float* b1 = (const float*)d_in[7];
    const float* W2 = (const float*)d_in[8];
    const float* b2 = (const float*)d_in[9];
    const float* W3 = (const float*)d_in[10];
    const float* b3 = (const float*)d_in[11];
    float* out = (float*)d_out;

    // workspace layout: h [B*K1] fp32 (3 MB), partial [KC*B*H1] fp32 (4 MB)
    float* h       = (float*)d_ws;
    float* partial = h + (size_t)BB * K1;

    hipLaunchKernelGGL(feat_kernel, dim3(BB, 2), dim3(192), 0, stream,
                       (const float4*)x1, (const float4*)x2, s1, e1, s2, e2,
                       (float4*)h);
    hipLaunchKernelGGL(layer1_kernel, dim3(BB / RT, KC), dim3(H1), 0, stream,
                       h, W1, partial);
    hipLaunchKernelGGL(head_kernel, dim3(BB), dim3(H1), 0, stream,
                       partial, b1, W2, b2, W3, b3, out);
}

// Round 2
// 636.822 us; speedup vs baseline: 1.0674x; 1.0674x over previous
//
#include <hip/hip_runtime.h>
#include <hip/hip_bf16.h>

// Problem constants (xlm-roberta-base temprel head)
#define BB 256      // batch
#define SS 512      // seq len
#define DD 768      // hidden
#define H1 256      // linear1 out
#define H2 64       // linear2 out
#define LL 4        // labels
#define K1 (4*DD)   // 3072 = concat feature dim
#define KC 32       // K-chunks for layer1 split-K (512 blocks -> 2/CU)
#define KCH (K1/KC) // 96
#define RT 16       // rows per block in layer1

// ---------------------------------------------------------------------------
// Kernel 1: event features. grid (B, 2), block (192, 4) = 768 threads.
// Span positions split across threadIdx.y (4 groups) -> serial depth <=8,
// LDS reduce. h[b, w*1536+0:768] = CLS; h[b, w*1536+768:1536] = segment mean.
// ---------------------------------------------------------------------------
__global__ __launch_bounds__(768, 1)
void feat_kernel(const float4* __restrict__ x1,
                 const float4* __restrict__ x2,
                 const int* __restrict__ s1, const int* __restrict__ e1,
                 const int* __restrict__ s2, const int* __restrict__ e2,
                 float4* __restrict__ h) {
    const int b = blockIdx.x;
    const int which = blockIdx.y;
    const int t = threadIdx.x;  // 0..191  (768/4 float4 columns)
    const int g = threadIdx.y;  // 0..3    span-position group
    const float4* x = which ? x2 : x1;
    int s = which ? s2[b] : s1[b];
    int e = which ? e2[b] : e1[b];
    e = max(e, s + 1);              // reference: end = max(end, start+1)
    const int sc = max(s, 0);
    const int ec = min(e, SS);
    const int n  = max(ec - sc, 1); // reference: cnt = max(mask.sum, 1)

    const float4* xrow = x + (size_t)b * SS * (DD/4);
    float4 acc = make_float4(0.f, 0.f, 0.f, 0.f);
    for (int p = sc + g; p < ec; p += 4) {
        float4 v = xrow[(size_t)p * (DD/4) + t];
        acc.x += v.x; acc.y += v.y; acc.z += v.z; acc.w += v.w;
    }

    __shared__ float4 red[4][DD/4];
    red[g][t] = acc;
    __syncthreads();

    if (g == 0) {
        float4 r1 = red[1][t], r2 = red[2][t], r3 = red[3][t];
        acc.x += r1.x + r2.x + r3.x;
        acc.y += r1.y + r2.y + r3.y;
        acc.z += r1.z + r2.z + r3.z;
        acc.w += r1.w + r2.w + r3.w;
        const float inv = 1.0f / (float)n;
        acc.x *= inv; acc.y *= inv; acc.z *= inv; acc.w *= inv;

        float4* hrow = h + (size_t)b * (K1/4) + which * (2*DD/4);
        hrow[t] = xrow[t];            // CLS
        hrow[(DD/4) + t] = acc;       // segment mean
    }
}

// ---------------------------------------------------------------------------
// Kernel 2: layer-1 split-K partial GEMM.
// grid (B/RT=16, KC=32) = 512 blocks (2/CU, 2 waves/SIMD), block = 256.
// Each block: rows r0..r0+15, all 256 cols, K-chunk of 96.
// h[] accesses are block-uniform -> scalar loads; W1 reads coalesced per k.
// partial[kc][row][col] fp32.
// ---------------------------------------------------------------------------
__global__ __launch_bounds__(256, 2)
void layer1_kernel(const float* __restrict__ h,
                   const float* __restrict__ W1,
                   float* __restrict__ partial) {
    const int rt = blockIdx.x;    // row tile
    const int kc = blockIdx.y;    // k chunk
    const int j  = threadIdx.x;   // output column 0..255
    const int r0 = rt * RT;
    const int k0 = kc * KCH;

    float acc[RT];
#pragma unroll
    for (int r = 0; r < RT; ++r) acc[r] = 0.f;

    const float* w = W1 + (size_t)k0 * H1 + j;
    const float* hp = h + (size_t)r0 * K1 + k0;
#pragma unroll 8
    for (int k = 0; k < KCH; ++k) {
        const float wv = w[(size_t)k * H1];
#pragma unroll
        for (int r = 0; r < RT; ++r) {
            acc[r] = fmaf(hp[(size_t)r * K1 + k], wv, acc[r]);
        }
    }

    float* p = partial + ((size_t)kc * BB + r0) * H1 + j;
#pragma unroll
    for (int r = 0; r < RT; ++r) p[(size_t)r * H1] = acc[r];
}

// ---------------------------------------------------------------------------
// Kernel 3: fused head. grid (B), block 256.
// reduce split-K partials + b1 + relu -> a1[256] (LDS)
// a1 @ W2 (4-way k-split over all 256 threads) + b2, relu -> a2[64]
// a2 @ W3 + b3 -> logits[4] -> softmax -> out[b, 0:4]
// ---------------------------------------------------------------------------
__global__ __launch_bounds__(256, 4)
void head_kernel(const float* __restrict__ partial,
                 const float* __restrict__ b1,
                 const float* __restrict__ W2,
                 const float* __restrict__ b2,
                 const float* __restrict__ W3,
                 const float* __restrict__ b3,
                 float* __restrict__ out) {
    const int b = blockIdx.x;
    const int t = threadIdx.x;
    __shared__ float a1[H1];
    __shared__ float a2p[4][H2];
    __shared__ float a2[H2];
    __shared__ float lg[LL];

    float v = b1[t];
#pragma unroll
    for (int kc = 0; kc < KC; ++kc)
        v += partial[((size_t)kc * BB + b) * H1 + t];
    a1[t] = fmaxf(v, 0.f);
    __syncthreads();

    // layer 2: output j = t&63, k-range part = t>>6 (64 k each)
    {
        const int j = t & (H2 - 1);
        const int part = t >> 6;
        const int kbeg = part * (H1 / 4);
        float acc = 0.f;
#pragma unroll 8
        for (int k = kbeg; k < kbeg + (H1 / 4); ++k)
            acc = fmaf(a1[k], W2[k * H2 + j], acc);
        a2p[part][j] = acc;
    }
    __syncthreads();

    if (t < H2) {
        float s = b2[t] + a2p[0][t] + a2p[1][t] + a2p[2][t] + a2p[3][t];
        a2[t] = fmaxf(s, 0.f);
    }
    __syncthreads();

    if (t < LL) {
        float acc = b3[t];
#pragma unroll
        for (int k = 0; k < H2; ++k)
            acc = fmaf(a2[k], W3[k * LL + t], acc);
        lg[t] = acc;
    }
    __syncthreads();

    if (t < LL) {
        const float m = fmaxf(fmaxf(lg[0], lg[1]), fmaxf(lg[2], lg[3]));
        const float sum = expf(lg[0] - m) + expf(lg[1] - m) +
                          expf(lg[2] - m) + expf(lg[3] - m);
        out[b * LL + t] = expf(lg[t] - m) / sum;
    }
}

extern "C" void kernel_launch(void* const* d_in, const int* in_sizes, int n_in,
                              void* d_out, int out_size, void* d_ws, size_t ws_size,
                              hipStream_t stream) {
    const float* x1 = (const float*)d_in[0];
    const float* x2 = (const float*)d_in[1];
    const int*   s1 = (const int*)d_in[2];
    const int*   e1 = (const int*)d_in[3];
    const int*   s2 = (const int*)d_in[4];
    const int*   e2 = (const int*)d_in[5];
    const float* W1 = (const float*)d_in[6];
    const float* b1 = (const float*)d_in[7];
    const float* W2 = (const float*)d_in[8];
    const float* b2 = (const float*)d_in[9];
    const float* W3 = (const float*)d_in[10];
    const float* b3 = (const float*)d_in[11];
    float* out = (float*)d_out;

    // workspace layout: h [B*K1] fp32 (3 MB), partial [KC*B*H1] fp32 (8 MB)
    float* h       = (float*)d_ws;
    float* partial = h + (size_t)BB * K1;

    hipLaunchKernelGGL(feat_kernel, dim3(BB, 2), dim3(192, 4), 0, stream,
                       (const float4*)x1, (const float4*)x2, s1, e1, s2, e2,
                       (float4*)h);
    hipLaunchKernelGGL(layer1_kernel, dim3(BB / RT, KC), dim3(H1), 0, stream,
                       h, W1, partial);
    hipLaunchKernelGGL(head_kernel, dim3(BB), dim3(H1), 0, stream,
                       partial, b1, W2, b2, W3, b3, out);
}